// Round 15
// baseline (216.655 us; speedup 1.0000x reference)
//
#include <hip/hip_runtime.h>
#include <math.h>

// Problem constants
#define NB 32768
#define NC 100
#define NK 8
#define ND 512
#define ALPHA 22.0f      // Neumann split: Ahat = ALPHA*(I - M); eig(Ahat) in [19.8, ~24.3]
#define NEU_K3 6         // eig(M) in [-0.105, 0.1] -> rel err ~1.3e-6, tolerance is ~0.03
#define CTP 104          // centersT padded row stride
// Pipeline (4 launches). hn redistributed across prep kernels (R13: 196.7us).
//   k_prep_class 100 class blocks + hn rows 0..13567      (3492 blocks)
//   k_T1M        250 work blocks  + hn rows 13568..27135  (3642 blocks)
//   k_solveW     112 class blocks + hn rows 27136..32767  (464 blocks, 1024thr)
//   k_main_mfma  128x160 tile, R13's proven 2-block/CU dbuf-sync schedule, but
//                A now lives in REGISTERS with depth-1 prefetch issued right
//                AFTER each barrier (consumed after the NEXT barrier -> full
//                compute phase of latency hiding; R6's variant issued A right
//                BEFORE the barrier and its vmcnt(0) exposed the latency).
//                B stays DMA->LDS dbuf. LDS traffic/kc 108KB -> 60KB.
// Main-GEMM schedule ledger: R13 dbuf-sync 56.0-56.6 PROVEN; counted-coarse
// 59.5 FAIL; A-direct-exposed 76 FAIL; 256x160 triple-buf 1blk/CU 74 FAIL.

typedef __attribute__((ext_vector_type(8))) short short8;
typedef __attribute__((ext_vector_type(4))) float f32x4;

__device__ __forceinline__ void gl_lds16(const void* g, void* l) {
    __builtin_amdgcn_global_load_lds(
        (const __attribute__((address_space(1))) void*)g,
        (__attribute__((address_space(3))) void*)l, 16, 0, 0);
}

__device__ __forceinline__ float warpReduceSum(float v) {
#pragma unroll
    for (int off = 32; off > 0; off >>= 1) v += __shfl_xor(v, off);
    return v;
}

__device__ float blockReduceSum256(float v, float* red) {
    int tid = threadIdx.x;
    v = warpReduceSum(v);
    __syncthreads();
    if ((tid & 63) == 0) red[tid >> 6] = v;
    __syncthreads();
    return red[0] + red[1] + red[2] + red[3];
}

__device__ __forceinline__ unsigned short f2bf(float x) {
    unsigned u = __float_as_uint(x);
    u = (u + 0x7FFFu + ((u >> 16) & 1u)) >> 16;
    return (unsigned short)u;
}
__device__ __forceinline__ float bf2f(unsigned short h) {
    return __uint_as_float(((unsigned)h) << 16);
}

// ---------------- bf16 input normalization (one row per wave) ----------------
__device__ __forceinline__ void hn_row(const float* __restrict__ h,
                                       unsigned short* __restrict__ hnb,
                                       int r, int lane) {
    const float4* hp = reinterpret_cast<const float4*>(h + (size_t)r * ND);
    float4 v0 = hp[lane * 2];
    float4 v1 = hp[lane * 2 + 1];
    float s = v0.x * v0.x + v0.y * v0.y + v0.z * v0.z + v0.w * v0.w
            + v1.x * v1.x + v1.y * v1.y + v1.z * v1.z + v1.w * v1.w;
    s = warpReduceSum(s);
    float inv = 1.0f / fmaxf(sqrtf(s), 1e-8f);
    uint4 o;
    o.x = (unsigned)f2bf(v0.x * inv) | ((unsigned)f2bf(v0.y * inv) << 16);
    o.y = (unsigned)f2bf(v0.z * inv) | ((unsigned)f2bf(v0.w * inv) << 16);
    o.z = (unsigned)f2bf(v1.x * inv) | ((unsigned)f2bf(v1.y * inv) << 16);
    o.w = (unsigned)f2bf(v1.z * inv) | ((unsigned)f2bf(v1.w * inv) << 16);
    reinterpret_cast<uint4*>(hnb + (size_t)r * ND)[lane] = o;
}

// 256-thread variant: 4 rows per block
__device__ __forceinline__ void hn_block4(const float* __restrict__ h,
                                          unsigned short* __restrict__ hnb, int blk) {
    int tid = threadIdx.x;
    hn_row(h, hnb, blk * 4 + (tid >> 6), tid & 63);
}

// hn row ranges per kernel
#define HN_T1M_BASE   13568     // rows 13568..27135 (3392 blocks of 4)
#define HN_SOLVE_BASE 27136     // rows 27136..32767 (352 blocks of 16)

// ------------------------- prep kernels (fp32) -------------------------

// Pn rows + centers + centersT(padded) + b_same + Bp proto rows; blocks >= NC do hn.
__global__ void k_prep_class(const float* __restrict__ protos, float* __restrict__ X,
                             float* __restrict__ centersT, unsigned short* __restrict__ Bp,
                             const float* __restrict__ h, unsigned short* __restrict__ hnb) {
    int c = blockIdx.x;
    if (c >= NC) { hn_block4(h, hnb, c - NC); return; }   // rows 0..13567
    __shared__ float red[4];
    int tid = threadIdx.x;
    const float eps = 1e-8f;
    float pv0[NK], pv1[NK];
#pragma unroll
    for (int k = 0; k < NK; ++k) {
        pv0[k] = protos[(c * NK + k) * ND + tid];
        pv1[k] = protos[(c * NK + k) * ND + tid + 256];
    }
    float sv0 = 0.f, sv1 = 0.f;
#pragma unroll
    for (int k = 0; k < NK; ++k) {
        float ss = blockReduceSum256(pv0[k] * pv0[k] + pv1[k] * pv1[k], red);
        float inv = 1.0f / fmaxf(sqrtf(ss), eps);
        pv0[k] *= inv; pv1[k] *= inv;
        X[(c * NK + k) * ND + tid] = pv0[k];
        X[(c * NK + k) * ND + tid + 256] = pv1[k];
        Bp[(size_t)(c * 10 + k) * ND + tid] = f2bf(pv0[k]);
        Bp[(size_t)(c * 10 + k) * ND + tid + 256] = f2bf(pv1[k]);
        sv0 += pv0[k]; sv1 += pv1[k];
    }
    float ssum = blockReduceSum256(sv0 * sv0 + sv1 * sv1, red);
    float mnorm = sqrtf(ssum) * 0.125f;
    float cinv = 0.125f / fmaxf(mnorm, eps);
    float* centers = X + 800 * ND;
    float c0 = sv0 * cinv, c1 = sv1 * cinv;
    centers[c * ND + tid] = c0;
    centers[c * ND + tid + 256] = c1;
    centersT[tid * CTP + c] = c0;
    centersT[(tid + 256) * CTP + c] = c1;
    const float ws = 0.5f / 8.0f;
    float* bvec = X + 900 * ND;          // holds b_same (bvec corr applied in k_solveW)
    bvec[c * ND + tid] = ws * sv0;
    bvec[c * ND + tid + 256] = ws * sv1;
}

// T1[j][i] = centers_i . X_j for j=0..999; rows 800..899 also emit M = I - Ahat/ALPHA.
// centersT (padded [512][104]) staged into LDS in 4 d-tiles shared by all 4 waves.
__global__ __launch_bounds__(256) void k_T1M(const float* __restrict__ X,
                                             const float* __restrict__ centersT,
                                             float* __restrict__ T1, float* __restrict__ M,
                                             const float* __restrict__ h,
                                             unsigned short* __restrict__ hnb) {
    int blk = blockIdx.x;
    if (blk >= 250) { hn_block4(h, hnb, blk - 250 + HN_T1M_BASE / 4); return; }
    __shared__ float xs[4][ND];
    __shared__ float cT[128 * CTP];
    int tid = threadIdx.x;
    int wave = tid >> 6, lane = tid & 63;
    int j = blk * 4 + wave;
    reinterpret_cast<float4*>(xs[wave])[lane * 2] =
        reinterpret_cast<const float4*>(X + (size_t)j * ND)[lane * 2];
    reinterpret_cast<float4*>(xs[wave])[lane * 2 + 1] =
        reinterpret_cast<const float4*>(X + (size_t)j * ND)[lane * 2 + 1];
    int i0 = lane, i1 = lane + 64;
    int i1c = (i1 < NC) ? i1 : 0;
    float s0 = 0.f, s1 = 0.f;
#pragma unroll
    for (int dt = 0; dt < 4; ++dt) {
        __syncthreads();   // waves done with previous tile (and xs staged, dt=0)
        for (int idx = tid; idx < 128 * CTP / 4; idx += 256)
            reinterpret_cast<float4*>(cT)[idx] =
                reinterpret_cast<const float4*>(centersT + dt * 128 * CTP)[idx];
        __syncthreads();
#pragma unroll 8
        for (int dd = 0; dd < 128; ++dd) {
            float xv = xs[wave][dt * 128 + dd];
            s0 = fmaf(xv, cT[dd * CTP + i0], s0);
            s1 = fmaf(xv, cT[dd * CTP + i1c], s1);
        }
    }
    T1[j * NC + i0] = s0;
    if (i1 < NC) T1[j * NC + i1] = s1;
    if (j >= 800 && j < 900) {
        int ci = j - 800;
        float a0 = s0 + ((i0 == ci) ? 19.8f : 0.f);
        M[ci * NC + i0] = ((i0 == ci) ? 1.f : 0.f) - a0 * (1.0f / ALPHA);
        if (i1 < NC) {
            float a1 = s1 + ((i1 == ci) ? 19.8f : 0.f);
            M[ci * NC + i1] = ((i1 == ci) ? 1.f : 0.f) - a1 * (1.0f / ALPHA);
        }
    }
}

// Per class c, 1024 threads (16 waves): all long chains split for latency hiding
// (R11: 64us -> <56us). Blocks >= 112 do hn (16 rows each, waves 0..15).
__global__ __launch_bounds__(1024) void k_solveW(const float* __restrict__ X,
                                                 const float* __restrict__ T1,
                                                 const float* __restrict__ M,
                                                 unsigned short* __restrict__ Bp,
                                                 const float* __restrict__ h,
                                                 unsigned short* __restrict__ hnb) {
    int c = blockIdx.x, tid = threadIdx.x;
    if (c >= 112) {   // hn rows 27136..32767
        hn_row(h, hnb, HN_SOLVE_BASE + (c - 112) * 16 + (tid >> 6), tid & 63);
        return;
    }
    if (c >= NC) {  // zero pad slots 100..111
        uint4 z = {0, 0, 0, 0};
        for (int idx = tid; idx < 10 * ND / 8; idx += 1024)
            reinterpret_cast<uint4*>(Bp + (size_t)c * 10 * ND)[idx] = z;
        return;
    }
    const float wo = 0.5f / 99.0f;
    __shared__ float Msh[NC * 108];       // 43.2KB
    __shared__ float Xs[10 * 516];        // 20.6KB
    __shared__ float T1s[10 * 104];
    __shared__ float T2s[10 * 104];
    __shared__ float pbuf[2][10][104];    // 8.3KB: one row per wave
    __shared__ float Sc[4][100];          // T1csum partials
    __shared__ float Gp[8][100];          // gram partials
    __shared__ float cp[2][512];          // epilogue csum partials
    __shared__ float sp[2][512];          // epilogue qdot partials
    __shared__ float G[10][10];
    __shared__ float SL[9 * 10];
    __shared__ float zL[9];
    __shared__ float q[104];
    __shared__ float rs1[10];
    __shared__ int bestIdx;
    for (int idx = tid; idx < 10 * 128; idx += 1024) {
        int a = idx >> 7, p = idx & 127;
        int row = (a < 8) ? (c * 8 + a) : ((a == 8) ? (800 + c) : (900 + c));
        reinterpret_cast<float4*>(&Xs[a * 516])[p] =
            reinterpret_cast<const float4*>(X + (size_t)row * ND)[p];
    }
    for (int idx = tid; idx < NC * NC; idx += 1024) {
        int i = idx / NC, mm = idx - i * NC;
        Msh[i * 108 + mm] = M[idx];
    }
    for (int idx = tid; idx < 10 * NC; idx += 1024) {
        int a = idx / NC, i = idx - a * NC;
        int row = (a < 8) ? (c * 8 + a) : ((a == 8) ? (800 + c) : (900 + c));
        T1s[a * 104 + i] = T1[row * NC + i];
    }
    if (tid < 400) {   // T1csum 4-way cc-split partials
        int i = tid % 100, sl = tid / 100;
        float s = 0.f;
#pragma unroll 5
        for (int cc = sl * 25; cc < sl * 25 + 25; ++cc) s += T1[(800 + cc) * NC + i];
        Sc[sl][i] = s;
    }
    __syncthreads();
    // bvec-basis correction of T1 row 9 (commutes with Ahat^{-1})
    if (tid < NC) {
        float s1c = Sc[0][tid] + Sc[1][tid] + Sc[2][tid] + Sc[3][tid];
        T1s[9 * 104 + tid] -= wo * (s1c - T1s[8 * 104 + tid]);
    }
    __syncthreads();
    // Neumann: T2s[r] = Ahat^{-1} T1s[r], ONE ROW PER WAVE (waves 0..9 parallel)
    // Inner loop identical to R7-proven form (mm += 4, exactly covers 0..99).
    {
        int wave = tid >> 6, lane = tid & 63;
        if (wave < 10) {
            int r = wave;
            int i0 = lane, i1 = lane + 64;
            int i1c = (i1 < NC) ? i1 : 0;
            float t0 = T1s[r * 104 + i0];
            float t1v = (i1 < NC) ? T1s[r * 104 + i1] : 0.f;
            float s0 = t0, s1 = t1v;
            pbuf[0][r][i0] = t0;
            if (i1 < NC) pbuf[0][r][i1] = t1v;
            int cur = 0;
            for (int it = 0; it < NEU_K3; ++it) {
                const float* p = pbuf[cur][r];
                float y0 = 0.f, y1 = 0.f;
#pragma unroll 5
                for (int mm = 0; mm < NC; mm += 4) {
                    float4 pv = *reinterpret_cast<const float4*>(p + mm);
                    float4 a0 = *reinterpret_cast<const float4*>(&Msh[i0 * 108 + mm]);
                    float4 a1 = *reinterpret_cast<const float4*>(&Msh[i1c * 108 + mm]);
                    y0 = fmaf(a0.x, pv.x, y0); y0 = fmaf(a0.y, pv.y, y0);
                    y0 = fmaf(a0.z, pv.z, y0); y0 = fmaf(a0.w, pv.w, y0);
                    y1 = fmaf(a1.x, pv.x, y1); y1 = fmaf(a1.y, pv.y, y1);
                    y1 = fmaf(a1.z, pv.z, y1); y1 = fmaf(a1.w, pv.w, y1);
                }
                s0 += y0; s1 += y1;
                int nxt = cur ^ 1;
                pbuf[nxt][r][i0] = y0;
                if (i1 < NC) pbuf[nxt][r][i1] = y1;
                cur = nxt;
            }
            T2s[r * 104 + i0] = s0 * (1.0f / ALPHA);
            if (i1 < NC) T2s[r * 104 + i1] = s1 * (1.0f / ALPHA);
        }
    }
    __syncthreads();
    // gram: 8-way d-slice partials (800 threads) | rs1 (800..809)
    if (tid < 800) {
        int pair = tid % 100, sl = tid / 100;
        int a = pair / 10, b = pair - a * 10;
        float s = 0.f;
#pragma unroll 4
        for (int d = sl * 64; d < sl * 64 + 64; ++d)
            s += Xs[a * 516 + d] * Xs[b * 516 + d];
        Gp[sl][pair] = s;
    } else if (tid < 810) {
        int a = tid - 800;
        float s = 0.f;
#pragma unroll 4
        for (int i = 0; i < NC; ++i) s += T1s[a * 104 + i];
        rs1[a] = s;
    }
    __syncthreads();
    if (tid < 100) {
        float g = 0.f;
#pragma unroll
        for (int sl = 0; sl < 8; ++sl) g += Gp[sl][tid];
        G[tid / 10][tid % 10] = g;
    }
    __syncthreads();
    if (tid < 90) {
        int a = tid / 10, b = tid - (tid / 10) * 10;
        float g = G[a][b];
        if (b == 9) g -= wo * (rs1[a] - T1s[a * 104 + c]);
        float s = 0.f;
#pragma unroll 4
        for (int i = 0; i < NC; ++i) s += T1s[a * 104 + i] * T2s[b * 104 + i];
        float val = (g - s) * 10.0f;   // 1/ridge
        if (b == a) val += (a < 8) ? 16.0f : -198.0f;  // D^{-1}
        SL[tid] = val;
    }
    __syncthreads();
    // ---- parallel 9x9 Gaussian elimination with partial pivoting (R10-proven) ----
    {
        int r = tid / 10, j = tid - (tid / 10) * 10;
        for (int p = 0; p < 9; ++p) {
            if (tid < 64) {
                float v = -1.f; int idx = p;
                if (tid < 9 && tid >= p) { v = fabsf(SL[tid * 10 + p]); idx = tid; }
#pragma unroll
                for (int off = 8; off > 0; off >>= 1) {
                    float ov = __shfl_down(v, off);
                    int oi = __shfl_down(idx, off);
                    if (ov > v) { v = ov; idx = oi; }
                }
                if (tid == 0) bestIdx = idx;
            }
            __syncthreads();
            int best = bestIdx;
            if (best != p && tid < 10) {
                float t = SL[p * 10 + tid];
                SL[p * 10 + tid] = SL[best * 10 + tid];
                SL[best * 10 + tid] = t;
            }
            __syncthreads();
            bool act = (tid < 90) && (r > p) && (j >= p);
            float f = 0.f, pv = 0.f;
            if (act) {
                f = SL[r * 10 + p] / SL[p * 10 + p];
                pv = SL[p * 10 + j];
            }
            __syncthreads();
            if (act) SL[r * 10 + j] -= f * pv;
            __syncthreads();
        }
        if (tid < 64) {
            for (int p = 8; p >= 0; --p) {
                float prod = 0.f;
                if (tid > p && tid < 9) prod = SL[p * 10 + tid] * zL[tid];
#pragma unroll
                for (int off = 8; off > 0; off >>= 1) prod += __shfl_down(prod, off);
                if (tid == 0) zL[p] = (SL[p * 10 + 9] - prod) / SL[p * 10 + p];
            }
        }
    }
    __syncthreads();
    if (tid < NC) {
        float s = T2s[9 * 104 + tid];
#pragma unroll
        for (int a = 0; a < 9; ++a) s -= zL[a] * T2s[a * 104 + tid];
        q[tid] = s;
    }
    __syncthreads();
    // epilogue: fused csum + qdot single pass over centers, 2-way i-split
    {
        int d = tid & 511, half = tid >> 9;
        const float* centers = X + 800 * ND;
        float cs = 0.f, sv = 0.f;
#pragma unroll 5
        for (int i = half * 50; i < half * 50 + 50; ++i) {
            float cv = centers[i * ND + d];
            cs += cv;
            sv = fmaf(cv, q[i], sv);
        }
        cp[half][d] = cs;
        sp[half][d] = sv;
    }
    __syncthreads();
    if (tid < 512) {
        int d = tid;
        float cs = cp[0][d] + cp[1][d];
        float sv = sp[0][d] + sp[1][d];
        float u = Xs[9 * 516 + d] - wo * (cs - Xs[8 * 516 + d]);
#pragma unroll
        for (int a = 0; a < 9; ++a) u -= zL[a] * Xs[a * 516 + d];
        float w = (u - sv) * 10.0f;
        unsigned short hi = f2bf(w);
        Bp[(size_t)(c * 10 + 8) * ND + d] = hi;
        Bp[(size_t)(c * 10 + 9) * ND + d] = f2bf(w - bf2f(hi));
    }
}

// ------------------------- main MFMA GEMM + fused epilogue -------------------------
// 128 rows x 160 cols per block, BK=64, 4 waves (rh,ch), 2 blocks/CU.
// B: DMA->LDS double-buffer (2x20KB), one __syncthreads per kc (R13 schedule).
// A: REGISTER double-buffer — A(kc+1) loads issue right AFTER kc's barrier and
// are consumed after the NEXT barrier (full compute phase of latency hiding;
// R6's failure was issuing them right BEFORE the barrier -> vmcnt(0) exposure).
// kc loop fully unrolled so the afA/afB selection is compile-time (no scratch).
// LDS 43KB (B dbuf + epilogue Cs[64][163] overlay). A addressing = R6-verified.

__global__ __launch_bounds__(256, 2) void k_main_mfma(
        const unsigned short* __restrict__ hnb, const unsigned short* __restrict__ Bp,
        float* __restrict__ out) {
    __shared__ __align__(16) char smem[43008];
    float* Cs = (float*)smem;

    int tid = threadIdx.x;
    int wave = tid >> 6, lane = tid & 63;
    int m = lane & 15, g = lane >> 4;
    int rs = m & 7;
    int rh = wave & 1, ch = wave >> 1;

    // XCD swizzle: the 7 col-blocks of one row-block land on one XCD
    int id = blockIdx.x;
    int xcd = id & 7, kk2 = id >> 3;
    int cb = kk2 % 7;
    int rb = (kk2 / 7) * 8 + xcd;
    int r0 = rb * 128;

    int rsub = lane >> 3;            // row within 8-row chunk
    int osw = (lane & 7) ^ rsub;     // swizzled source k-octet (B staging)

    f32x4 acc[4][5] = {};

    // stage B tile kc into buffer p: 5 DMA chunks per thread
    auto issueB = [&](int kc, int p) {
        unsigned short* Bs = (unsigned short*)(smem + p * 20480);
#pragma unroll
        for (int q2 = 0; q2 < 5; ++q2) {
            int chk = wave * 5 + q2;
            gl_lds16(Bp + (size_t)(cb * 160 + chk * 8 + rsub) * ND + kc * 64 + osw * 8,
                     Bs + chk * 512);
        }
    };

    // A base: this wave's fragment rows (rh half, row m within each 16-row tile)
    const unsigned short* arow = hnb + (size_t)(r0 + rh * 64 + m) * ND + g * 8;

    short8 afA[2][4], afB[2][4];     // register double buffer for A fragments
    // prologue: A(0) into afA; B(0) staged. Exposed drain once at kc=0 (~1 load).
#pragma unroll
    for (int rt = 0; rt < 4; ++rt)
#pragma unroll
        for (int kk = 0; kk < 2; ++kk)
            afA[kk][rt] = *reinterpret_cast<const short8*>(
                arow + (size_t)rt * 16 * ND + kk * 32);
    issueB(0, 0);

#pragma unroll
    for (int kc = 0; kc < 8; ++kc) {
        int cur = kc & 1;
        __syncthreads();                 // B(kc) staged; A(kc) loads (issued in
                                         // kc-1's compute) complete with ~0 wait
        if (kc < 7) issueB(kc + 1, cur ^ 1);
        auto& afc = (kc & 1) ? afB : afA;    // compile-time (loop unrolled)
        auto& afn = (kc & 1) ? afA : afB;
        if (kc < 7) {
            // prefetch A(kc+1): in flight across this whole compute phase
#pragma unroll
            for (int rt = 0; rt < 4; ++rt)
#pragma unroll
                for (int kk = 0; kk < 2; ++kk)
                    afn[kk][rt] = *reinterpret_cast<const short8*>(
                        arow + (size_t)rt * 16 * ND + (kc + 1) * 64 + kk * 32);
        }
        unsigned short* Bs = (unsigned short*)(smem + cur * 20480);
#pragma unroll
        for (int kk = 0; kk < 2; ++kk) {
            short8 bfr[5];
#pragma unroll
            for (int ct = 0; ct < 5; ++ct)
                bfr[ct] = *reinterpret_cast<const short8*>(
                    Bs + (ch * 80 + ct * 16 + m) * 64 + (((kk << 2) + g) ^ rs) * 8);
#pragma unroll
            for (int rt = 0; rt < 4; ++rt)
#pragma unroll
                for (int ct = 0; ct < 5; ++ct)
                    acc[rt][ct] = __builtin_amdgcn_mfma_f32_16x16x32_bf16(
                        afc[kk][rt], bfr[ct], acc[rt][ct], 0, 0, 0);
        }
    }

    // two-pass epilogue, one 64-row half at a time (C/D layout: col=lane&15, row=g*4+reg)
    int cl = tid & 15;
    int c = cb * 16 + cl;
#pragma unroll
    for (int hh = 0; hh < 2; ++hh) {
        __syncthreads();
        if (rh == hh) {
#pragma unroll
            for (int rt = 0; rt < 4; ++rt)
#pragma unroll
                for (int ct = 0; ct < 5; ++ct)
#pragma unroll
                    for (int reg = 0; reg < 4; ++reg) {
                        int lr = rt * 16 + g * 4 + reg;
                        int lc = ch * 80 + ct * 16 + m;
                        Cs[lr * 163 + lc] = acc[rt][ct][reg];
                    }
        }
        __syncthreads();
#pragma unroll
        for (int q2 = 0; q2 < 4; ++q2) {
            int r = (tid >> 4) + q2 * 16;
            float v[10];
#pragma unroll
            for (int j = 0; j < 10; ++j) v[j] = Cs[r * 163 + cl * 10 + j];
            float mx = v[0];
#pragma unroll
            for (int j = 1; j < 8; ++j) mx = fmaxf(mx, v[j]);
            float se = 0.f, sec = 0.f;
#pragma unroll
            for (int j = 0; j < 8; ++j) {
                float e = __expf((v[j] - mx) * 20.0f);  // 1/SUB_T
                se += e; sec += e * v[j];
            }
            float res = v[8] + v[9];
            if (c < NC)
                out[(size_t)(r0 + hh * 64 + r) * NC + c] = (sec / se + res) * (1.0f / 0.07f);
        }
    }
}

extern "C" void kernel_launch(void* const* d_in, const int* in_sizes, int n_in,
                              void* d_out, int out_size, void* d_ws, size_t ws_size,
                              hipStream_t stream) {
    (void)in_sizes; (void)n_in; (void)out_size; (void)ws_size;
    const float* h = (const float*)d_in[0];
    const float* protos = (const float*)d_in[1];
    float* out = (float*)d_out;
    float* ws = (float*)d_ws;

    float* X        = ws;                  // 512000 (Pn | centers | b_same)
    float* centersT = X + 512000;          // 53248  [512][104] padded
    float* M        = centersT + 53248;    // 10000
    float* T1       = M + 10000;           // 100000 [1000][100]
    unsigned short* hnb = (unsigned short*)(T1 + 100000);   // 32768*512 bf16
    unsigned short* Bp  = hnb + (size_t)NB * ND;            // 1120*512 bf16

    // hn split: prep_class rows 0..13567 (3392 blks), T1M rows 13568..27135
    // (3392 blks), solveW rows 27136..32767 (352 blks x 16 rows)
    k_prep_class<<<NC + 3392, 256, 0, stream>>>(protos, X, centersT, Bp, h, hnb);
    k_T1M<<<250 + 3392, 256, 0, stream>>>(X, centersT, T1, M, h, hnb);
    k_solveW<<<112 + 352, 1024, 0, stream>>>(X, T1, M, Bp, h, hnb);
    k_main_mfma<<<1792, 256, 0, stream>>>(hnb, Bp, out);
}

// Round 16
// 196.055 us; speedup vs baseline: 1.1051x; 1.1051x over previous
//
#include <hip/hip_runtime.h>
#include <math.h>

// Problem constants
#define NB 32768
#define NC 100
#define NK 8
#define ND 512
#define ALPHA 22.0f      // Neumann split: Ahat = ALPHA*(I - M); eig(Ahat) in [19.8, ~24.3]
#define NEU_K3 6         // eig(M) in [-0.105, 0.1] -> rel err ~1.3e-6, tolerance is ~0.03
#define CTP 104          // centersT padded row stride
// Pipeline (4 launches). hn redistributed across prep kernels (R13: 196.7us).
//   k_prep_class 100 class blocks + hn rows 0..13567      (3492 blocks)
//   k_T1M        250 work blocks  + hn rows 13568..27135  (3642 blocks)
//   k_solveW     112 class blocks + hn rows 27136..32767  (464 blocks, 1024thr)
//   k_main_mfma  128x160-tile bf16 MFMA GEMM — R13-PROVEN structure (56.0-56.6us).
// Main-GEMM schedule ledger (do not retry): R13 dbuf-sync 56.0-56.6 PROVEN;
// counted-coarse 59.5 FAIL; A-direct-exposed 76 FAIL; 256x160 triple-buf 74 FAIL;
// A-reg-dbuf post-barrier 74.7 FAIL. Per-wave global A-loads and 1-block/CU
// both break the inter-block overlap that hides the barrier drain.

typedef __attribute__((ext_vector_type(8))) short short8;
typedef __attribute__((ext_vector_type(4))) float f32x4;

__device__ __forceinline__ void gl_lds16(const void* g, void* l) {
    __builtin_amdgcn_global_load_lds(
        (const __attribute__((address_space(1))) void*)g,
        (__attribute__((address_space(3))) void*)l, 16, 0, 0);
}

__device__ __forceinline__ float warpReduceSum(float v) {
#pragma unroll
    for (int off = 32; off > 0; off >>= 1) v += __shfl_xor(v, off);
    return v;
}

__device__ float blockReduceSum256(float v, float* red) {
    int tid = threadIdx.x;
    v = warpReduceSum(v);
    __syncthreads();
    if ((tid & 63) == 0) red[tid >> 6] = v;
    __syncthreads();
    return red[0] + red[1] + red[2] + red[3];
}

__device__ __forceinline__ unsigned short f2bf(float x) {
    unsigned u = __float_as_uint(x);
    u = (u + 0x7FFFu + ((u >> 16) & 1u)) >> 16;
    return (unsigned short)u;
}
__device__ __forceinline__ float bf2f(unsigned short h) {
    return __uint_as_float(((unsigned)h) << 16);
}

// ---------------- bf16 input normalization (one row per wave) ----------------
__device__ __forceinline__ void hn_row(const float* __restrict__ h,
                                       unsigned short* __restrict__ hnb,
                                       int r, int lane) {
    const float4* hp = reinterpret_cast<const float4*>(h + (size_t)r * ND);
    float4 v0 = hp[lane * 2];
    float4 v1 = hp[lane * 2 + 1];
    float s = v0.x * v0.x + v0.y * v0.y + v0.z * v0.z + v0.w * v0.w
            + v1.x * v1.x + v1.y * v1.y + v1.z * v1.z + v1.w * v1.w;
    s = warpReduceSum(s);
    float inv = 1.0f / fmaxf(sqrtf(s), 1e-8f);
    uint4 o;
    o.x = (unsigned)f2bf(v0.x * inv) | ((unsigned)f2bf(v0.y * inv) << 16);
    o.y = (unsigned)f2bf(v0.z * inv) | ((unsigned)f2bf(v0.w * inv) << 16);
    o.z = (unsigned)f2bf(v1.x * inv) | ((unsigned)f2bf(v1.y * inv) << 16);
    o.w = (unsigned)f2bf(v1.z * inv) | ((unsigned)f2bf(v1.w * inv) << 16);
    reinterpret_cast<uint4*>(hnb + (size_t)r * ND)[lane] = o;
}

// 256-thread variant: 4 rows per block
__device__ __forceinline__ void hn_block4(const float* __restrict__ h,
                                          unsigned short* __restrict__ hnb, int blk) {
    int tid = threadIdx.x;
    hn_row(h, hnb, blk * 4 + (tid >> 6), tid & 63);
}

// hn row ranges per kernel
#define HN_T1M_BASE   13568     // rows 13568..27135 (3392 blocks of 4)
#define HN_SOLVE_BASE 27136     // rows 27136..32767 (352 blocks of 16)

// ------------------------- prep kernels (fp32) -------------------------

// Pn rows + centers + centersT(padded) + b_same + Bp proto rows; blocks >= NC do hn.
__global__ void k_prep_class(const float* __restrict__ protos, float* __restrict__ X,
                             float* __restrict__ centersT, unsigned short* __restrict__ Bp,
                             const float* __restrict__ h, unsigned short* __restrict__ hnb) {
    int c = blockIdx.x;
    if (c >= NC) { hn_block4(h, hnb, c - NC); return; }   // rows 0..13567
    __shared__ float red[4];
    int tid = threadIdx.x;
    const float eps = 1e-8f;
    float pv0[NK], pv1[NK];
#pragma unroll
    for (int k = 0; k < NK; ++k) {
        pv0[k] = protos[(c * NK + k) * ND + tid];
        pv1[k] = protos[(c * NK + k) * ND + tid + 256];
    }
    float sv0 = 0.f, sv1 = 0.f;
#pragma unroll
    for (int k = 0; k < NK; ++k) {
        float ss = blockReduceSum256(pv0[k] * pv0[k] + pv1[k] * pv1[k], red);
        float inv = 1.0f / fmaxf(sqrtf(ss), eps);
        pv0[k] *= inv; pv1[k] *= inv;
        X[(c * NK + k) * ND + tid] = pv0[k];
        X[(c * NK + k) * ND + tid + 256] = pv1[k];
        Bp[(size_t)(c * 10 + k) * ND + tid] = f2bf(pv0[k]);
        Bp[(size_t)(c * 10 + k) * ND + tid + 256] = f2bf(pv1[k]);
        sv0 += pv0[k]; sv1 += pv1[k];
    }
    float ssum = blockReduceSum256(sv0 * sv0 + sv1 * sv1, red);
    float mnorm = sqrtf(ssum) * 0.125f;
    float cinv = 0.125f / fmaxf(mnorm, eps);
    float* centers = X + 800 * ND;
    float c0 = sv0 * cinv, c1 = sv1 * cinv;
    centers[c * ND + tid] = c0;
    centers[c * ND + tid + 256] = c1;
    centersT[tid * CTP + c] = c0;
    centersT[(tid + 256) * CTP + c] = c1;
    const float ws = 0.5f / 8.0f;
    float* bvec = X + 900 * ND;          // holds b_same (bvec corr applied in k_solveW)
    bvec[c * ND + tid] = ws * sv0;
    bvec[c * ND + tid + 256] = ws * sv1;
}

// T1[j][i] = centers_i . X_j for j=0..999; rows 800..899 also emit M = I - Ahat/ALPHA.
// centersT (padded [512][104]) staged into LDS in 4 d-tiles shared by all 4 waves.
__global__ __launch_bounds__(256) void k_T1M(const float* __restrict__ X,
                                             const float* __restrict__ centersT,
                                             float* __restrict__ T1, float* __restrict__ M,
                                             const float* __restrict__ h,
                                             unsigned short* __restrict__ hnb) {
    int blk = blockIdx.x;
    if (blk >= 250) { hn_block4(h, hnb, blk - 250 + HN_T1M_BASE / 4); return; }
    __shared__ float xs[4][ND];
    __shared__ float cT[128 * CTP];
    int tid = threadIdx.x;
    int wave = tid >> 6, lane = tid & 63;
    int j = blk * 4 + wave;
    reinterpret_cast<float4*>(xs[wave])[lane * 2] =
        reinterpret_cast<const float4*>(X + (size_t)j * ND)[lane * 2];
    reinterpret_cast<float4*>(xs[wave])[lane * 2 + 1] =
        reinterpret_cast<const float4*>(X + (size_t)j * ND)[lane * 2 + 1];
    int i0 = lane, i1 = lane + 64;
    int i1c = (i1 < NC) ? i1 : 0;
    float s0 = 0.f, s1 = 0.f;
#pragma unroll
    for (int dt = 0; dt < 4; ++dt) {
        __syncthreads();   // waves done with previous tile (and xs staged, dt=0)
        for (int idx = tid; idx < 128 * CTP / 4; idx += 256)
            reinterpret_cast<float4*>(cT)[idx] =
                reinterpret_cast<const float4*>(centersT + dt * 128 * CTP)[idx];
        __syncthreads();
#pragma unroll 8
        for (int dd = 0; dd < 128; ++dd) {
            float xv = xs[wave][dt * 128 + dd];
            s0 = fmaf(xv, cT[dd * CTP + i0], s0);
            s1 = fmaf(xv, cT[dd * CTP + i1c], s1);
        }
    }
    T1[j * NC + i0] = s0;
    if (i1 < NC) T1[j * NC + i1] = s1;
    if (j >= 800 && j < 900) {
        int ci = j - 800;
        float a0 = s0 + ((i0 == ci) ? 19.8f : 0.f);
        M[ci * NC + i0] = ((i0 == ci) ? 1.f : 0.f) - a0 * (1.0f / ALPHA);
        if (i1 < NC) {
            float a1 = s1 + ((i1 == ci) ? 19.8f : 0.f);
            M[ci * NC + i1] = ((i1 == ci) ? 1.f : 0.f) - a1 * (1.0f / ALPHA);
        }
    }
}

// Per class c, 1024 threads (16 waves): all long chains split for latency hiding
// (R11: 64us -> <56us). Blocks >= 112 do hn (16 rows each, waves 0..15).
__global__ __launch_bounds__(1024) void k_solveW(const float* __restrict__ X,
                                                 const float* __restrict__ T1,
                                                 const float* __restrict__ M,
                                                 unsigned short* __restrict__ Bp,
                                                 const float* __restrict__ h,
                                                 unsigned short* __restrict__ hnb) {
    int c = blockIdx.x, tid = threadIdx.x;
    if (c >= 112) {   // hn rows 27136..32767
        hn_row(h, hnb, HN_SOLVE_BASE + (c - 112) * 16 + (tid >> 6), tid & 63);
        return;
    }
    if (c >= NC) {  // zero pad slots 100..111
        uint4 z = {0, 0, 0, 0};
        for (int idx = tid; idx < 10 * ND / 8; idx += 1024)
            reinterpret_cast<uint4*>(Bp + (size_t)c * 10 * ND)[idx] = z;
        return;
    }
    const float wo = 0.5f / 99.0f;
    __shared__ float Msh[NC * 108];       // 43.2KB
    __shared__ float Xs[10 * 516];        // 20.6KB
    __shared__ float T1s[10 * 104];
    __shared__ float T2s[10 * 104];
    __shared__ float pbuf[2][10][104];    // 8.3KB: one row per wave
    __shared__ float Sc[4][100];          // T1csum partials
    __shared__ float Gp[8][100];          // gram partials
    __shared__ float cp[2][512];          // epilogue csum partials
    __shared__ float sp[2][512];          // epilogue qdot partials
    __shared__ float G[10][10];
    __shared__ float SL[9 * 10];
    __shared__ float zL[9];
    __shared__ float q[104];
    __shared__ float rs1[10];
    __shared__ int bestIdx;
    for (int idx = tid; idx < 10 * 128; idx += 1024) {
        int a = idx >> 7, p = idx & 127;
        int row = (a < 8) ? (c * 8 + a) : ((a == 8) ? (800 + c) : (900 + c));
        reinterpret_cast<float4*>(&Xs[a * 516])[p] =
            reinterpret_cast<const float4*>(X + (size_t)row * ND)[p];
    }
    for (int idx = tid; idx < NC * NC; idx += 1024) {
        int i = idx / NC, mm = idx - i * NC;
        Msh[i * 108 + mm] = M[idx];
    }
    for (int idx = tid; idx < 10 * NC; idx += 1024) {
        int a = idx / NC, i = idx - a * NC;
        int row = (a < 8) ? (c * 8 + a) : ((a == 8) ? (800 + c) : (900 + c));
        T1s[a * 104 + i] = T1[row * NC + i];
    }
    if (tid < 400) {   // T1csum 4-way cc-split partials
        int i = tid % 100, sl = tid / 100;
        float s = 0.f;
#pragma unroll 5
        for (int cc = sl * 25; cc < sl * 25 + 25; ++cc) s += T1[(800 + cc) * NC + i];
        Sc[sl][i] = s;
    }
    __syncthreads();
    // bvec-basis correction of T1 row 9 (commutes with Ahat^{-1})
    if (tid < NC) {
        float s1c = Sc[0][tid] + Sc[1][tid] + Sc[2][tid] + Sc[3][tid];
        T1s[9 * 104 + tid] -= wo * (s1c - T1s[8 * 104 + tid]);
    }
    __syncthreads();
    // Neumann: T2s[r] = Ahat^{-1} T1s[r], ONE ROW PER WAVE (waves 0..9 parallel)
    // Inner loop identical to R7-proven form (mm += 4, exactly covers 0..99).
    {
        int wave = tid >> 6, lane = tid & 63;
        if (wave < 10) {
            int r = wave;
            int i0 = lane, i1 = lane + 64;
            int i1c = (i1 < NC) ? i1 : 0;
            float t0 = T1s[r * 104 + i0];
            float t1v = (i1 < NC) ? T1s[r * 104 + i1] : 0.f;
            float s0 = t0, s1 = t1v;
            pbuf[0][r][i0] = t0;
            if (i1 < NC) pbuf[0][r][i1] = t1v;
            int cur = 0;
            for (int it = 0; it < NEU_K3; ++it) {
                const float* p = pbuf[cur][r];
                float y0 = 0.f, y1 = 0.f;
#pragma unroll 5
                for (int mm = 0; mm < NC; mm += 4) {
                    float4 pv = *reinterpret_cast<const float4*>(p + mm);
                    float4 a0 = *reinterpret_cast<const float4*>(&Msh[i0 * 108 + mm]);
                    float4 a1 = *reinterpret_cast<const float4*>(&Msh[i1c * 108 + mm]);
                    y0 = fmaf(a0.x, pv.x, y0); y0 = fmaf(a0.y, pv.y, y0);
                    y0 = fmaf(a0.z, pv.z, y0); y0 = fmaf(a0.w, pv.w, y0);
                    y1 = fmaf(a1.x, pv.x, y1); y1 = fmaf(a1.y, pv.y, y1);
                    y1 = fmaf(a1.z, pv.z, y1); y1 = fmaf(a1.w, pv.w, y1);
                }
                s0 += y0; s1 += y1;
                int nxt = cur ^ 1;
                pbuf[nxt][r][i0] = y0;
                if (i1 < NC) pbuf[nxt][r][i1] = y1;
                cur = nxt;
            }
            T2s[r * 104 + i0] = s0 * (1.0f / ALPHA);
            if (i1 < NC) T2s[r * 104 + i1] = s1 * (1.0f / ALPHA);
        }
    }
    __syncthreads();
    // gram: 8-way d-slice partials (800 threads) | rs1 (800..809)
    if (tid < 800) {
        int pair = tid % 100, sl = tid / 100;
        int a = pair / 10, b = pair - a * 10;
        float s = 0.f;
#pragma unroll 4
        for (int d = sl * 64; d < sl * 64 + 64; ++d)
            s += Xs[a * 516 + d] * Xs[b * 516 + d];
        Gp[sl][pair] = s;
    } else if (tid < 810) {
        int a = tid - 800;
        float s = 0.f;
#pragma unroll 4
        for (int i = 0; i < NC; ++i) s += T1s[a * 104 + i];
        rs1[a] = s;
    }
    __syncthreads();
    if (tid < 100) {
        float g = 0.f;
#pragma unroll
        for (int sl = 0; sl < 8; ++sl) g += Gp[sl][tid];
        G[tid / 10][tid % 10] = g;
    }
    __syncthreads();
    if (tid < 90) {
        int a = tid / 10, b = tid - (tid / 10) * 10;
        float g = G[a][b];
        if (b == 9) g -= wo * (rs1[a] - T1s[a * 104 + c]);
        float s = 0.f;
#pragma unroll 4
        for (int i = 0; i < NC; ++i) s += T1s[a * 104 + i] * T2s[b * 104 + i];
        float val = (g - s) * 10.0f;   // 1/ridge
        if (b == a) val += (a < 8) ? 16.0f : -198.0f;  // D^{-1}
        SL[tid] = val;
    }
    __syncthreads();
    // ---- parallel 9x9 Gaussian elimination with partial pivoting (R10-proven) ----
    {
        int r = tid / 10, j = tid - (tid / 10) * 10;
        for (int p = 0; p < 9; ++p) {
            if (tid < 64) {
                float v = -1.f; int idx = p;
                if (tid < 9 && tid >= p) { v = fabsf(SL[tid * 10 + p]); idx = tid; }
#pragma unroll
                for (int off = 8; off > 0; off >>= 1) {
                    float ov = __shfl_down(v, off);
                    int oi = __shfl_down(idx, off);
                    if (ov > v) { v = ov; idx = oi; }
                }
                if (tid == 0) bestIdx = idx;
            }
            __syncthreads();
            int best = bestIdx;
            if (best != p && tid < 10) {
                float t = SL[p * 10 + tid];
                SL[p * 10 + tid] = SL[best * 10 + tid];
                SL[best * 10 + tid] = t;
            }
            __syncthreads();
            bool act = (tid < 90) && (r > p) && (j >= p);
            float f = 0.f, pv = 0.f;
            if (act) {
                f = SL[r * 10 + p] / SL[p * 10 + p];
                pv = SL[p * 10 + j];
            }
            __syncthreads();
            if (act) SL[r * 10 + j] -= f * pv;
            __syncthreads();
        }
        if (tid < 64) {
            for (int p = 8; p >= 0; --p) {
                float prod = 0.f;
                if (tid > p && tid < 9) prod = SL[p * 10 + tid] * zL[tid];
#pragma unroll
                for (int off = 8; off > 0; off >>= 1) prod += __shfl_down(prod, off);
                if (tid == 0) zL[p] = (SL[p * 10 + 9] - prod) / SL[p * 10 + p];
            }
        }
    }
    __syncthreads();
    if (tid < NC) {
        float s = T2s[9 * 104 + tid];
#pragma unroll
        for (int a = 0; a < 9; ++a) s -= zL[a] * T2s[a * 104 + tid];
        q[tid] = s;
    }
    __syncthreads();
    // epilogue: fused csum + qdot single pass over centers, 2-way i-split
    {
        int d = tid & 511, half = tid >> 9;
        const float* centers = X + 800 * ND;
        float cs = 0.f, sv = 0.f;
#pragma unroll 5
        for (int i = half * 50; i < half * 50 + 50; ++i) {
            float cv = centers[i * ND + d];
            cs += cv;
            sv = fmaf(cv, q[i], sv);
        }
        cp[half][d] = cs;
        sp[half][d] = sv;
    }
    __syncthreads();
    if (tid < 512) {
        int d = tid;
        float cs = cp[0][d] + cp[1][d];
        float sv = sp[0][d] + sp[1][d];
        float u = Xs[9 * 516 + d] - wo * (cs - Xs[8 * 516 + d]);
#pragma unroll
        for (int a = 0; a < 9; ++a) u -= zL[a] * Xs[a * 516 + d];
        float w = (u - sv) * 10.0f;
        unsigned short hi = f2bf(w);
        Bp[(size_t)(c * 10 + 8) * ND + d] = hi;
        Bp[(size_t)(c * 10 + 9) * ND + d] = f2bf(w - bf2f(hi));
    }
}

// ------------------------- main MFMA GEMM + fused epilogue -------------------------
// 128 rows x 160 cols per block, BK=64, double-buffered async DMA staging (one
// __syncthreads per kc — R13-PROVEN structure, 56.0-56.6us). XOR-octet swizzled
// LDS, XCD-aware block swizzle. LDS: 2 x (A 16KB + B 20KB) = 72KB, 2 blocks/CU;
// epilogue reuses Cs[64][163] f32 twice.

__global__ __launch_bounds__(256, 2) void k_main_mfma(
        const unsigned short* __restrict__ hnb, const unsigned short* __restrict__ Bp,
        float* __restrict__ out) {
    __shared__ __align__(16) char smem[73728];
    float* Cs = (float*)smem;

    int tid = threadIdx.x;
    int wave = tid >> 6, lane = tid & 63;
    int m = lane & 15, g = lane >> 4;
    int rs = m & 7;
    int rh = wave & 1, ch = wave >> 1;

    // XCD swizzle: the 7 col-blocks of one row-block land on one XCD
    int id = blockIdx.x;
    int xcd = id & 7, kk2 = id >> 3;
    int cb = kk2 % 7;
    int rb = (kk2 / 7) * 8 + xcd;
    int r0 = rb * 128;

    int rsub = lane >> 3;            // row within 8-row chunk
    int osw = (lane & 7) ^ rsub;     // swizzled source k-octet

    f32x4 acc[4][5] = {};

    // stage kc into buffer p (A: 16 chunks/4 per wave; B: 20 chunks/5 per wave)
    auto issue = [&](int kc, int p) {
        unsigned short* As = (unsigned short*)(smem + p * 36864);
        unsigned short* Bs = As + 8192;
#pragma unroll
        for (int q2 = 0; q2 < 4; ++q2) {
            int chk = wave * 4 + q2;
            gl_lds16(hnb + (size_t)(r0 + chk * 8 + rsub) * ND + kc * 64 + osw * 8,
                     As + chk * 512);
        }
#pragma unroll
        for (int q2 = 0; q2 < 5; ++q2) {
            int chk = wave * 5 + q2;
            gl_lds16(Bp + (size_t)(cb * 160 + chk * 8 + rsub) * ND + kc * 64 + osw * 8,
                     Bs + chk * 512);
        }
    };

    issue(0, 0);
    for (int kc = 0; kc < 8; ++kc) {
        int cur = kc & 1;
        __syncthreads();                 // drains own DMAs (vmcnt 0) + barrier
        if (kc < 7) issue(kc + 1, cur ^ 1);
        unsigned short* As = (unsigned short*)(smem + cur * 36864);
        unsigned short* Bs = As + 8192;
#pragma unroll
        for (int kk = 0; kk < 2; ++kk) {
            short8 af[4], bfr[5];
#pragma unroll
            for (int rt = 0; rt < 4; ++rt)
                af[rt] = *reinterpret_cast<const short8*>(
                    As + (rh * 64 + rt * 16 + m) * 64 + (((kk << 2) + g) ^ rs) * 8);
#pragma unroll
            for (int ct = 0; ct < 5; ++ct)
                bfr[ct] = *reinterpret_cast<const short8*>(
                    Bs + (ch * 80 + ct * 16 + m) * 64 + (((kk << 2) + g) ^ rs) * 8);
#pragma unroll
            for (int rt = 0; rt < 4; ++rt)
#pragma unroll
                for (int ct = 0; ct < 5; ++ct)
                    acc[rt][ct] = __builtin_amdgcn_mfma_f32_16x16x32_bf16(
                        af[rt], bfr[ct], acc[rt][ct], 0, 0, 0);
        }
    }

    // two-pass epilogue, one 64-row half at a time (C/D layout: col=lane&15, row=g*4+reg)
    int cl = tid & 15;
    int c = cb * 16 + cl;
#pragma unroll
    for (int hh = 0; hh < 2; ++hh) {
        __syncthreads();
        if (rh == hh) {
#pragma unroll
            for (int rt = 0; rt < 4; ++rt)
#pragma unroll
                for (int ct = 0; ct < 5; ++ct)
#pragma unroll
                    for (int reg = 0; reg < 4; ++reg) {
                        int lr = rt * 16 + g * 4 + reg;
                        int lc = ch * 80 + ct * 16 + m;
                        Cs[lr * 163 + lc] = acc[rt][ct][reg];
                    }
        }
        __syncthreads();
#pragma unroll
        for (int q2 = 0; q2 < 4; ++q2) {
            int r = (tid >> 4) + q2 * 16;
            float v[10];
#pragma unroll
            for (int j = 0; j < 10; ++j) v[j] = Cs[r * 163 + cl * 10 + j];
            float mx = v[0];
#pragma unroll
            for (int j = 1; j < 8; ++j) mx = fmaxf(mx, v[j]);
            float se = 0.f, sec = 0.f;
#pragma unroll
            for (int j = 0; j < 8; ++j) {
                float e = __expf((v[j] - mx) * 20.0f);  // 1/SUB_T
                se += e; sec += e * v[j];
            }
            float res = v[8] + v[9];
            if (c < NC)
                out[(size_t)(r0 + hh * 64 + r) * NC + c] = (sec / se + res) * (1.0f / 0.07f);
        }
    }
}

extern "C" void kernel_launch(void* const* d_in, const int* in_sizes, int n_in,
                              void* d_out, int out_size, void* d_ws, size_t ws_size,
                              hipStream_t stream) {
    (void)in_sizes; (void)n_in; (void)out_size; (void)ws_size;
    const float* h = (const float*)d_in[0];
    const float* protos = (const float*)d_in[1];
    float* out = (float*)d_out;
    float* ws = (float*)d_ws;

    float* X        = ws;                  // 512000 (Pn | centers | b_same)
    float* centersT = X + 512000;          // 53248  [512][104] padded
    float* M        = centersT + 53248;    // 10000
    float* T1       = M + 10000;           // 100000 [1000][100]
    unsigned short* hnb = (unsigned short*)(T1 + 100000);   // 32768*512 bf16
    unsigned short* Bp  = hnb + (size_t)NB * ND;            // 1120*512 bf16

    // hn split: prep_class rows 0..13567 (3392 blks), T1M rows 13568..27135
    // (3392 blks), solveW rows 27136..32767 (352 blks x 16 rows)
    k_prep_class<<<NC + 3392, 256, 0, stream>>>(protos, X, centersT, Bp, h, hnb);
    k_T1M<<<250 + 3392, 256, 0, stream>>>(X, centersT, T1, M, h, hnb);
    k_solveW<<<112 + 352, 1024, 0, stream>>>(X, T1, M, Bp, h, hnb);
    k_main_mfma<<<1792, 256, 0, stream>>>(hnb, Bp, out);
}